// Round 6
// baseline (543.705 us; speedup 1.0000x reference)
//
#include <hip/hip_runtime.h>
#include <cstdint>
#include <cstddef>

typedef __bf16 bf16_t;
typedef __attribute__((ext_vector_type(8))) __bf16 bf16x8;
typedef __attribute__((ext_vector_type(4))) __bf16 bf16x4;
typedef __attribute__((ext_vector_type(4))) float floatx4;

#define NB 32
#define NW 168
#define NM 2048
#define NHID 128
#define NBW (NB * NW)  // 5376
#define NGEMM 672      // 42 m-tiles x 16 n-tiles of 128^2
#define NMLPB 256      // 256-row mlp blocks

#define GLOAD_LDS16(g, l)                                          \
  __builtin_amdgcn_global_load_lds(                                \
      (const __attribute__((address_space(1))) void*)(g),          \
      (__attribute__((address_space(3))) void*)(l), 16, 0, 0)

// elementwise fp32 -> bf16 cast, n4 = n/4
__global__ void cast_bf16_kernel(const float* __restrict__ in, bf16_t* __restrict__ out, int n4) {
  int stride = gridDim.x * blockDim.x;
  for (int i = blockIdx.x * blockDim.x + threadIdx.x; i < n4; i += stride) {
    float4 v = ((const float4*)in)[i];
    bf16x4 o = {(bf16_t)v.x, (bf16_t)v.y, (bf16_t)v.z, (bf16_t)v.w};
    ((bf16x4*)out)[i] = o;
  }
}

// Fused x prep: read x [(bw)][m] fp32 once; write Xb [(bw)][m] bf16 (cast) and
// XT [m][(bw)] bf16 (transpose). 64x64 tiles.
__global__ void prep_x_kernel(const float* __restrict__ x, bf16_t* __restrict__ Xb,
                              bf16_t* __restrict__ XT) {
  __shared__ float tile[64][65];
  const int R = NBW, C = NM;
  int r0 = blockIdx.y * 64, c0 = blockIdx.x * 64;
  int t = threadIdx.x;
  int tr = t >> 4, tc4 = (t & 15) * 4;
#pragma unroll
  for (int p = 0; p < 4; ++p) {
    int row = p * 16 + tr;
    float4 v = *(const float4*)(x + (size_t)(r0 + row) * C + c0 + tc4);
    tile[row][tc4 + 0] = v.x;
    tile[row][tc4 + 1] = v.y;
    tile[row][tc4 + 2] = v.z;
    tile[row][tc4 + 3] = v.w;
    bf16x4 o = {(bf16_t)v.x, (bf16_t)v.y, (bf16_t)v.z, (bf16_t)v.w};
    *(bf16x4*)(Xb + (size_t)(r0 + row) * C + c0 + tc4) = o;
  }
  __syncthreads();
#pragma unroll
  for (int p = 0; p < 4; ++p) {
    int c = p * 16 + tr;
    bf16x4 o = {(bf16_t)tile[tc4 + 0][c], (bf16_t)tile[tc4 + 1][c],
                (bf16_t)tile[tc4 + 2][c], (bf16_t)tile[tc4 + 3][c]};
    *(bf16x4*)(XT + (size_t)(c0 + c) * R + r0 + tc4) = o;
  }
}

// ---------------------------------------------------------------------------
// mlp body: one 256-row MLP sub-block, 512 threads, ALL 8 waves compute
// (4m x 2n; wave out 64 rows x 64 hid). All 512 threads stage W1 (3072
// chunks = 6 per thread; pads zeroed). K=168 padded to 192, W1 in [kc][h]
// chunk layout with XOR swizzle. Barriers unconditional.
// ---------------------------------------------------------------------------
__device__ __forceinline__ void mlp_block(
    int tid, int r0, bf16_t* __restrict__ Bs,
    const bf16_t* __restrict__ T, const bf16_t* __restrict__ Wh,
    const float* __restrict__ b1h, const float* __restrict__ w2h, float b2v,
    float* __restrict__ out, int accumulate) {
  float* sred = (float*)(Bs + 24576);  // 512 floats after the 48KB W1 tile
  int lane = tid & 63, wv2 = tid >> 6;

  // stage 3072 chunks (incl. zero pads kc 21..23): 6 per thread
#pragma unroll
  for (int i = 0; i < 6; ++i) {
    int c = i * 512 + tid;
    if (c >= 2688) {
      int4 z = {0, 0, 0, 0};
      *(int4*)(Bs + (size_t)c * 8) = z;
    } else {
      int kc = c >> 7;
      int h = (c & 127) ^ ((kc & 3) << 2);
      GLOAD_LDS16(Wh + (size_t)h * NW + kc * 8, Bs + (size_t)(i * 512 + wv2 * 64) * 8);
    }
  }
  __syncthreads();  // staging (incl. async loads) complete

  {
    int wm = wv2 >> 1, wn = wv2 & 1;  // wm 0..3 (rows), wn 0..1 (hid)
    int quad = lane >> 4, l15 = lane & 15;
    const bf16_t* arow[4];
#pragma unroll
    for (int mi = 0; mi < 4; ++mi) {
      int R = r0 + wm * 64 + mi * 16 + l15;
      arow[mi] = T + (size_t)(R >> 5) * NBW + (size_t)(R & 31) * NW + quad * 8;
    }
    floatx4 zero4 = {0.f, 0.f, 0.f, 0.f};
    floatx4 acc[4][4];
#pragma unroll
    for (int mi = 0; mi < 4; ++mi)
#pragma unroll
      for (int ni = 0; ni < 4; ++ni) acc[mi][ni] = zero4;

#pragma unroll
    for (int kb = 0; kb < 192; kb += 32) {
      int kc = (kb >> 3) + quad;
      bf16x8 af[4], bf[4];
#pragma unroll
      for (int mi = 0; mi < 4; ++mi)
        af[mi] = *(const bf16x8*)(arow[mi] + kb);  // k>=168 reads garbage; B pad=0
#pragma unroll
      for (int ni = 0; ni < 4; ++ni) {
        int hpos = (wn * 64 + ni * 16 + l15) ^ ((kc & 3) << 2);
        bf[ni] = *(const bf16x8*)(Bs + (size_t)(kc * 128 + hpos) * 8);
      }
#pragma unroll
      for (int mi = 0; mi < 4; ++mi)
#pragma unroll
        for (int ni = 0; ni < 4; ++ni)
          acc[mi][ni] = __builtin_amdgcn_mfma_f32_16x16x32_bf16(af[mi], bf[ni], acc[mi][ni], 0, 0, 0);
    }

    // epilogue: relu(H + b1) dot W2 per row
    float part[4][4];
#pragma unroll
    for (int mi = 0; mi < 4; ++mi)
#pragma unroll
      for (int r = 0; r < 4; ++r) part[mi][r] = 0.f;
#pragma unroll
    for (int ni = 0; ni < 4; ++ni) {
      int col = wn * 64 + ni * 16 + l15;
      float b1v = b1h[col];
      float w2v = w2h[col];
#pragma unroll
      for (int mi = 0; mi < 4; ++mi)
#pragma unroll
        for (int r = 0; r < 4; ++r) {
          float h = acc[mi][ni][r] + b1v;
          h = h > 0.f ? h : 0.f;
          part[mi][r] += h * w2v;
        }
    }
#pragma unroll
    for (int off = 1; off < 16; off <<= 1)
#pragma unroll
      for (int mi = 0; mi < 4; ++mi)
#pragma unroll
        for (int r = 0; r < 4; ++r) part[mi][r] += __shfl_xor(part[mi][r], off);
    if (l15 == 0) {
#pragma unroll
      for (int mi = 0; mi < 4; ++mi)
#pragma unroll
        for (int r = 0; r < 4; ++r) sred[wv2 * 64 + mi * 16 + quad * 4 + r] = part[mi][r];
    }
  }
  __syncthreads();
  if (tid < 256) {
    int wm = tid >> 6;
    int lr = tid & 63;
    float v = sred[(wm * 2) * 64 + lr] + sred[(wm * 2 + 1) * 64 + lr] + b2v;
    int R = r0 + wm * 64 + lr;
    int idx = (R & 31) * NM + (R >> 5);  // out[b*M + m]
    if (accumulate)
      out[idx] += v;
    else
      out[idx] = v;
  }
}

// ---------------------------------------------------------------------------
// Fused launch, round 6: CO-RESIDENCY restructure. Blocks [0,NGEMM) run a
// 128x128 BK=32 NT GEMM tile (512 thr, 8 waves 2Mx4N, wave-out 64x32,
// 3-buffer LDS rotation, 48KB); blocks [NGEMM,+NMLPB) run one 256-row MLP
// block (51.2KB). LDS union 51.2KB + VGPR<=128 (launch_bounds 512,4) ->
// 2 blocks/CU: when one block stalls on barrier/vmcnt, the co-resident
// block's waves keep the MFMA/LDS pipes fed (m114/m97 mechanism) -- the
// lever 5 rounds of schedule tuning at 1 block/CU could not reach.
// GEMM pipeline: stage tile t+2 at top of iter t (2 gload_lds/thread);
// counted vmcnt(2) at iter end drains exactly tile t+1; buffer (t+2)%3
// overwrite races checked (its readers drained before iter t-1's end
// barrier). XCD-bijective block swizzle (672=8*84), n-fastest within chunk.
// ---------------------------------------------------------------------------
#define STG(c_, t_)                                                          \
  do {                                                                       \
    GLOAD_LDS16(aS + (size_t)(t_) * 32, lds + (c_) * 8192 + wv * 512);       \
    GLOAD_LDS16(bS + (size_t)(t_) * 32, lds + (c_) * 8192 + 4096 + wv * 512);\
  } while (0)

__global__ __launch_bounds__(512, 4) void fused_gemm_mlp_kernel(
    const bf16_t* __restrict__ A, const bf16_t* __restrict__ Bt,
    bf16_t* __restrict__ C, bf16_t* __restrict__ Ct,
    int K, int lda, int ldb, int ldc, int ldct, int write_c,
    const bf16_t* __restrict__ T, const bf16_t* __restrict__ W1b,
    const float* __restrict__ b1, const float* __restrict__ W2,
    const float* __restrict__ b2, float* __restrict__ out,
    int hop, int accumulate) {
  __shared__ bf16_t lds[25600];  // 51.2 KB union (gemm 48KB | mlp 48KB+2KB sred)
  const int bx = blockIdx.x;
  const int tid = threadIdx.x;

  if (bx >= NGEMM) {
    int j = bx - NGEMM;
    mlp_block(tid, j * 256, lds, T, W1b + (size_t)hop * NHID * NW,
              b1 + hop * NHID, W2 + hop * NHID, b2[hop], out, accumulate);
    return;
  }

  // ---- GEMM path: 128x128 tile ----
  const int sid = (bx & 7) * 84 + (bx >> 3);  // bijective XCD swizzle (672=8*84)
  const int m0 = (sid >> 4) * 128, n0 = (sid & 15) * 128;
  const int lane = tid & 63, wv = tid >> 6;
  const int wm = wv >> 2, wn = wv & 3;  // wave out 64(m) x 32(n)
  const int quad = lane >> 4, l15 = lane & 15;

  // staging: thread stages chunk p=tid of each 128x32 panel (row=tid>>2,
  // slot=tid&3), source chunk pre-swizzled with f(row)=(row>>1)&3.
  const int srow = tid >> 2;
  const int scsw = (tid & 3) ^ ((srow >> 1) & 3);
  const bf16_t* aS = A + (size_t)(m0 + srow) * lda + scsw * 8;
  const bf16_t* bS = Bt + (size_t)(n0 + srow) * ldb + scsw * 8;

  // fragment read swizzle: slot = quad ^ ((l15>>1)&3) -> 8 lanes hit 8
  // distinct 16B slots per 128B (round-2-verified conflict-free).
  const int fsw = (quad ^ ((l15 >> 1) & 3)) * 8;

  floatx4 zero4 = {0.f, 0.f, 0.f, 0.f};
  floatx4 acc[4][2];
#pragma unroll
  for (int mi = 0; mi < 4; ++mi)
#pragma unroll
    for (int ni = 0; ni < 2; ++ni) acc[mi][ni] = zero4;

  // prologue: stage tiles 0,1 into bufs 0,1; vmcnt(2) -> tile0 landed.
  STG(0, 0);
  STG(1, 1);
  asm volatile("s_waitcnt vmcnt(2)" ::: "memory");
  __builtin_amdgcn_s_barrier();

  const int nk = K >> 5;  // K-tiles of 32
  int c = 0;
#pragma unroll 1
  for (int t = 0; t < nk; ++t) {
    int tt = (t + 2 < nk) ? t + 2 : 0;  // clamp: dummy re-stage keeps counts uniform
    int cn = c + 2; if (cn >= 3) cn -= 3;
    STG(cn, tt);
    const bf16_t* pa = lds + c * 8192;
    const bf16_t* pb = pa + 4096;
    bf16x8 af[4], bf[2];
#pragma unroll
    for (int ni = 0; ni < 2; ++ni)
      bf[ni] = *(const bf16x8*)(pb + (wn * 32 + ni * 16 + l15) * 32 + fsw);
#pragma unroll
    for (int mi = 0; mi < 4; ++mi)
      af[mi] = *(const bf16x8*)(pa + (wm * 64 + mi * 16 + l15) * 32 + fsw);
    __builtin_amdgcn_s_setprio(1);
#pragma unroll
    for (int mi = 0; mi < 4; ++mi)
#pragma unroll
      for (int ni = 0; ni < 2; ++ni)
        acc[mi][ni] = __builtin_amdgcn_mfma_f32_16x16x32_bf16(af[mi], bf[ni], acc[mi][ni], 0, 0, 0);
    __builtin_amdgcn_s_setprio(0);
    asm volatile("s_waitcnt vmcnt(2)" ::: "memory");  // tile t+1 landed
    __builtin_amdgcn_s_barrier();
    c = (c + 1 == 3) ? 0 : c + 1;
  }
  asm volatile("s_waitcnt vmcnt(0)" ::: "memory");

  // epilogue: C rows m0+wm*64+mi*16+quad*4+r, cols n0+wn*32+ni*16+l15
#pragma unroll
  for (int mi = 0; mi < 4; ++mi) {
#pragma unroll
    for (int ni = 0; ni < 2; ++ni) {
      int col = n0 + wn * 32 + ni * 16 + l15;
      int rowb = m0 + wm * 64 + mi * 16 + quad * 4;
      bf16x4 tv;
#pragma unroll
      for (int r = 0; r < 4; ++r) tv[r] = (bf16_t)acc[mi][ni][r];
      *(bf16x4*)(Ct + (size_t)col * ldct + rowb) = tv;
      if (write_c) {
#pragma unroll
        for (int r = 0; r < 4; ++r)
          C[(size_t)(rowb + r) * ldc + col] = tv[r];
      }
    }
  }
}

// Standalone MLP (hop 6 tail): 512-thread, 256-row blocks.
__global__ __launch_bounds__(512, 4) void mlp_score_kernel(
    const bf16_t* __restrict__ T, const bf16_t* __restrict__ W1b,
    const float* __restrict__ b1, const float* __restrict__ W2,
    const float* __restrict__ b2, float* __restrict__ out,
    int hop, int accumulate) {
  __shared__ bf16_t Bs[25600];  // 48KB W1 tile + 2KB sred
  mlp_block(threadIdx.x, blockIdx.x * 256, Bs, T,
            W1b + (size_t)hop * NHID * NW, b1 + hop * NHID, W2 + hop * NHID,
            b2[hop], out, accumulate);
}

extern "C" void kernel_launch(void* const* d_in, const int* in_sizes, int n_in,
                              void* d_out, int out_size, void* d_ws, size_t ws_size,
                              hipStream_t stream) {
  const float* x = (const float*)d_in[0];
  const float* L = (const float*)d_in[1];
  const float* W1 = (const float*)d_in[2];
  const float* b1 = (const float*)d_in[3];
  const float* W2 = (const float*)d_in[4];
  const float* b2 = (const float*)d_in[5];
  float* out = (float*)d_out;

  char* ws = (char*)d_ws;
  size_t off = 0;
  auto walloc = [&](size_t bytes) -> void* {
    off = (off + 255) & ~(size_t)255;
    void* p = ws + off;
    off += bytes;
    return p;
  };
  bf16_t* Xb = (bf16_t*)walloc((size_t)NBW * NM * 2);   // Tt_0 = x cast: [(b,w)][m]
  bf16_t* XT0 = (bf16_t*)walloc((size_t)NM * NBW * 2);  // [m][(b,w)] MLP input, buf 0
  bf16_t* XT1 = (bf16_t*)walloc((size_t)NM * NBW * 2);  // [m][(b,w)] MLP input, buf 1
  bf16_t* Lb = (bf16_t*)walloc((size_t)NM * NM * 2);    // L bf16 (NT B-operand)
  bf16_t* W1b = (bf16_t*)walloc((size_t)7 * NHID * NW * 2);
  bf16_t* Ta = (bf16_t*)walloc((size_t)NBW * NM * 2);   // ping-pong partner of Xb
  (void)ws_size; (void)in_sizes; (void)n_in; (void)out_size;

  prep_x_kernel<<<dim3(NM / 64, NBW / 64), dim3(256), 0, stream>>>(x, Xb, XT0);
  cast_bf16_kernel<<<dim3(1024), dim3(256), 0, stream>>>(L, Lb, NM * NM / 4);
  cast_bf16_kernel<<<dim3(64), dim3(256), 0, stream>>>(W1, W1b, 7 * NHID * NW / 4);

  // Fused chain: launch i computes gemm hop i (Tt_i + XT_i) on blocks
  // [0,672) and mlp hop i-1 (reading XT_{i-1}) on blocks [672,928).
  bf16_t* src = Xb;
  bf16_t* dst = Ta;
  bf16_t* xtprev = XT0;
  bf16_t* xtcur = XT1;
  for (int i = 1; i <= 6; ++i) {
    fused_gemm_mlp_kernel<<<dim3(NGEMM + NMLPB), dim3(512), 0, stream>>>(
        src, Lb, dst, xtcur, NM, NM, NM, NM, NBW, (i < 6) ? 1 : 0,
        xtprev, W1b, b1, W2, b2, out, i - 1, (i > 1) ? 1 : 0);
    bf16_t* t = src; src = dst; dst = t;
    t = xtprev; xtprev = xtcur; xtcur = t;
  }
  // tail: mlp hop 6 on the last XT
  mlp_score_kernel<<<dim3(NM * NB / 256), dim3(512), 0, stream>>>(
      xtprev, W1b, b1, W2, b2, out, 6, 1);
}

// Round 8
// 485.497 us; speedup vs baseline: 1.1199x; 1.1199x over previous
//
#include <hip/hip_runtime.h>
#include <cstdint>
#include <cstddef>

typedef __bf16 bf16_t;
typedef __attribute__((ext_vector_type(8))) __bf16 bf16x8;
typedef __attribute__((ext_vector_type(4))) __bf16 bf16x4;
typedef __attribute__((ext_vector_type(4))) float floatx4;
typedef __attribute__((ext_vector_type(16))) float floatx16;

#define NB 32
#define NW 168
#define NM 2048
#define NHID 128
#define NBW (NB * NW)  // 5376
#define NGEMM 168      // 21 m-tiles x 8 n-tiles of 256^2
#define NMLPB 256      // 256-row mlp blocks

#define GLOAD_LDS16(g, l)                                          \
  __builtin_amdgcn_global_load_lds(                                \
      (const __attribute__((address_space(1))) void*)(g),          \
      (__attribute__((address_space(3))) void*)(l), 16, 0, 0)

// ---------------------------------------------------------------------------
// Merged prep: blocks [0,2688) = prep_x 64x64 tiles (cast + transpose);
// [2688,3712) = cast L; [3712,3776) = cast W1. Deterministic: disjoint
// writes, block-uniform branches, barrier only in the tile branch.
// ---------------------------------------------------------------------------
__global__ void prep_all_kernel(const float* __restrict__ x, bf16_t* __restrict__ Xb,
                                bf16_t* __restrict__ XT, const float* __restrict__ L,
                                bf16_t* __restrict__ Lb, const float* __restrict__ W1,
                                bf16_t* __restrict__ W1b) {
  __shared__ float tile[64][65];
  const int bx = blockIdx.x;
  const int t = threadIdx.x;
  if (bx < 2688) {
    const int R = NBW, C = NM;
    int r0 = (bx >> 5) * 64, c0 = (bx & 31) * 64;
    int tr = t >> 4, tc4 = (t & 15) * 4;
#pragma unroll
    for (int p = 0; p < 4; ++p) {
      int row = p * 16 + tr;
      float4 v = *(const float4*)(x + (size_t)(r0 + row) * C + c0 + tc4);
      tile[row][tc4 + 0] = v.x;
      tile[row][tc4 + 1] = v.y;
      tile[row][tc4 + 2] = v.z;
      tile[row][tc4 + 3] = v.w;
      bf16x4 o = {(bf16_t)v.x, (bf16_t)v.y, (bf16_t)v.z, (bf16_t)v.w};
      *(bf16x4*)(Xb + (size_t)(r0 + row) * C + c0 + tc4) = o;
    }
    __syncthreads();
#pragma unroll
    for (int p = 0; p < 4; ++p) {
      int c = p * 16 + tr;
      bf16x4 o = {(bf16_t)tile[tc4 + 0][c], (bf16_t)tile[tc4 + 1][c],
                  (bf16_t)tile[tc4 + 2][c], (bf16_t)tile[tc4 + 3][c]};
      *(bf16x4*)(XT + (size_t)(c0 + c) * R + r0 + tc4) = o;
    }
  } else if (bx < 3712) {
    const int n4 = NM * NM / 4;
    for (int i = (bx - 2688) * 256 + t; i < n4; i += 1024 * 256) {
      float4 v = ((const float4*)L)[i];
      bf16x4 o = {(bf16_t)v.x, (bf16_t)v.y, (bf16_t)v.z, (bf16_t)v.w};
      ((bf16x4*)Lb)[i] = o;
    }
  } else {
    const int n4 = 7 * NHID * NW / 4;
    for (int i = (bx - 3712) * 256 + t; i < n4; i += 64 * 256) {
      float4 v = ((const float4*)W1)[i];
      bf16x4 o = {(bf16_t)v.x, (bf16_t)v.y, (bf16_t)v.z, (bf16_t)v.w};
      ((bf16x4*)W1b)[i] = o;
    }
  }
}

// ---------------------------------------------------------------------------
// mlp body (r6-verified): one 256-row MLP sub-block, 512 threads, ALL 8
// waves compute (4m x 2n; wave out 64 rows x 64 hid). All 512 threads stage
// W1 (3072 chunks = 6/thread; pads zeroed). K=168 padded to 192, W1 in
// [kc][h] chunk layout with XOR swizzle. Barriers unconditional.
// ---------------------------------------------------------------------------
__device__ __forceinline__ void mlp_block(
    int tid, int r0, bf16_t* __restrict__ Bs,
    const bf16_t* __restrict__ T, const bf16_t* __restrict__ Wh,
    const float* __restrict__ b1h, const float* __restrict__ w2h, float b2v,
    float* __restrict__ out, int accumulate) {
  float* sred = (float*)(Bs + 24576);  // 512 floats after the 48KB W1 tile
  int lane = tid & 63, wv2 = tid >> 6;

#pragma unroll
  for (int i = 0; i < 6; ++i) {
    int c = i * 512 + tid;
    if (c >= 2688) {
      int4 z = {0, 0, 0, 0};
      *(int4*)(Bs + (size_t)c * 8) = z;
    } else {
      int kc = c >> 7;
      int h = (c & 127) ^ ((kc & 3) << 2);
      GLOAD_LDS16(Wh + (size_t)h * NW + kc * 8, Bs + (size_t)(i * 512 + wv2 * 64) * 8);
    }
  }
  __syncthreads();  // staging (incl. async loads) complete

  {
    int wm = wv2 >> 1, wn = wv2 & 1;
    int quad = lane >> 4, l15 = lane & 15;
    const bf16_t* arow[4];
#pragma unroll
    for (int mi = 0; mi < 4; ++mi) {
      int R = r0 + wm * 64 + mi * 16 + l15;
      arow[mi] = T + (size_t)(R >> 5) * NBW + (size_t)(R & 31) * NW + quad * 8;
    }
    floatx4 zero4 = {0.f, 0.f, 0.f, 0.f};
    floatx4 acc[4][4];
#pragma unroll
    for (int mi = 0; mi < 4; ++mi)
#pragma unroll
      for (int ni = 0; ni < 4; ++ni) acc[mi][ni] = zero4;

#pragma unroll
    for (int kb = 0; kb < 192; kb += 32) {
      int kc = (kb >> 3) + quad;
      bf16x8 af[4], bf[4];
#pragma unroll
      for (int mi = 0; mi < 4; ++mi)
        af[mi] = *(const bf16x8*)(arow[mi] + kb);  // k>=168 reads garbage; B pad=0
#pragma unroll
      for (int ni = 0; ni < 4; ++ni) {
        int hpos = (wn * 64 + ni * 16 + l15) ^ ((kc & 3) << 2);
        bf[ni] = *(const bf16x8*)(Bs + (size_t)(kc * 128 + hpos) * 8);
      }
#pragma unroll
      for (int mi = 0; mi < 4; ++mi)
#pragma unroll
        for (int ni = 0; ni < 4; ++ni)
          acc[mi][ni] = __builtin_amdgcn_mfma_f32_16x16x32_bf16(af[mi], bf[ni], acc[mi][ni], 0, 0, 0);
    }

    float part[4][4];
#pragma unroll
    for (int mi = 0; mi < 4; ++mi)
#pragma unroll
      for (int r = 0; r < 4; ++r) part[mi][r] = 0.f;
#pragma unroll
    for (int ni = 0; ni < 4; ++ni) {
      int col = wn * 64 + ni * 16 + l15;
      float b1v = b1h[col];
      float w2v = w2h[col];
#pragma unroll
      for (int mi = 0; mi < 4; ++mi)
#pragma unroll
        for (int r = 0; r < 4; ++r) {
          float h = acc[mi][ni][r] + b1v;
          h = h > 0.f ? h : 0.f;
          part[mi][r] += h * w2v;
        }
    }
#pragma unroll
    for (int off = 1; off < 16; off <<= 1)
#pragma unroll
      for (int mi = 0; mi < 4; ++mi)
#pragma unroll
        for (int r = 0; r < 4; ++r) part[mi][r] += __shfl_xor(part[mi][r], off);
    if (l15 == 0) {
#pragma unroll
      for (int mi = 0; mi < 4; ++mi)
#pragma unroll
        for (int r = 0; r < 4; ++r) sred[wv2 * 64 + mi * 16 + quad * 4 + r] = part[mi][r];
    }
  }
  __syncthreads();
  if (tid < 256) {
    int wm = tid >> 6;
    int lr = tid & 63;
    float v = sred[(wm * 2) * 64 + lr] + sred[(wm * 2 + 1) * 64 + lr] + b2v;
    int R = r0 + wm * 64 + lr;
    int idx = (R & 31) * NM + (R >> 5);  // out[b*M + m]
    if (accumulate)
      out[idx] += v;
    else
      out[idx] = v;
  }
}

// ---------------------------------------------------------------------------
// Fused launch: blocks [0,NGEMM) run a 256x256 8-phase NT GEMM tile; blocks
// [NGEMM,+NMLPB) run one 256-row MLP sub-block of the PREVIOUS hop.
//
// Round-8 GEMM: round-4's verified sync skeleton (prefetch reads one phase
// ahead, double-barrier phases, VM6 at even-phase tops -- passed tripwire,
// best measured 64.4us), with the MFMA shape swapped 16x16x32 -> 32x32x16:
// 4060 vs 3378 FLOP/cyc/CU (m119 vs m06) = -17% matrix-pipe time at
// IDENTICAL fragment-read count (per K-half: 4 B + 8 A ds_read_b128 either
// way) and identical LDS layout/staging/swizzle. Fragment maps (32x32x16):
//   A: row = lane&31, k = (lane>>5)*8 + e  (1 b128/frag)
//   B: col = lane&31, k = (lane>>5)*8 + e
//   C/D: col = lane&31, row = (reg&3) + 8*(reg>>2) + 4*(lane>>5)
// Swizzle: panel row r chunk c holds global chunk c^((r>>1)&3); since rows
// are 32-aligned per fragment group, the XOR term is lane-constant
// ((l31>>1)&3). Conflict check: 8 consecutive lanes -> slots
// {c^0..c^3} u {4+c^0..4+c^3} = 8 distinct 16B slots. Conflict-free.
// ---------------------------------------------------------------------------
#define STAGE2(gbase, ld, t, ks, ldsbase)                                        \
  do {                                                                           \
    const bf16_t* _g = (gbase) + (size_t)(t) * 64 + (ks) * 32;                   \
    GLOAD_LDS16(_g, lds + (ldsbase) + (ks) * 8192 + wv * 512);                   \
    GLOAD_LDS16(_g + (size_t)128 * (ld),                                         \
                lds + (ldsbase) + (ks) * 8192 + 4096 + wv * 512);                \
  } while (0)

#define VM6 asm volatile("s_waitcnt vmcnt(6)" ::: "memory")
#define TOPB asm volatile("s_barrier" ::: "memory")
#define ENDB __builtin_amdgcn_s_barrier()

// A fragments for one (buf,ks,mh): dst[kk*2+mf] = A[mh*2+mf (32-row grp)][kk (16-k grp)]
#define RD_A4(dst, bufoff, ks, mh)                                               \
  _Pragma("unroll") for (int kk = 0; kk < 2; ++kk)                               \
      _Pragma("unroll") for (int mf = 0; mf < 2; ++mf)                           \
          dst[kk * 2 + mf] = *(const bf16x8*)(pA + (bufoff) + (ks) * 8192 +      \
              ((mh) * 2 + mf) * 1024 + (((kk * 2 + hi) ^ fsw32) << 3))

// B fragments for one (buf,ks): dst[kk*2+nf]
#define RD_B4(dst, bufoff, ks)                                                   \
  _Pragma("unroll") for (int kk = 0; kk < 2; ++kk)                               \
      _Pragma("unroll") for (int nf = 0; nf < 2; ++nf)                           \
          dst[kk * 2 + nf] = *(const bf16x8*)(pB + (bufoff) + (ks) * 8192 +      \
              nf * 1024 + (((kk * 2 + hi) ^ fsw32) << 3))

// 8x mfma_32x32x16 for one (ks,mh): acc[mh*2+mf][nf] over kk
#define MM(af_, bf_, mh)                                                         \
  do {                                                                           \
    __builtin_amdgcn_s_setprio(1);                                               \
    _Pragma("unroll") for (int mf = 0; mf < 2; ++mf)                             \
        _Pragma("unroll") for (int nf = 0; nf < 2; ++nf)                         \
            _Pragma("unroll") for (int kk = 0; kk < 2; ++kk)                     \
                acc[(mh) * 2 + mf][nf] = __builtin_amdgcn_mfma_f32_32x32x16_bf16(\
                    af_[kk * 2 + mf], bf_[kk * 2 + nf], acc[(mh) * 2 + mf][nf],  \
                    0, 0, 0);                                                    \
    __builtin_amdgcn_s_setprio(0);                                               \
  } while (0)

__global__ __launch_bounds__(512, 2) void fused_gemm_mlp_kernel(
    const bf16_t* __restrict__ A, const bf16_t* __restrict__ Bt,
    bf16_t* __restrict__ C, bf16_t* __restrict__ Ct,
    int K, int lda, int ldb, int ldc, int ldct, int write_c,
    const bf16_t* __restrict__ T, const bf16_t* __restrict__ W1b,
    const float* __restrict__ b1, const float* __restrict__ W2,
    const float* __restrict__ b2, float* __restrict__ out,
    int hop, int accumulate) {
  __shared__ bf16_t lds[65536];  // 128 KiB union
  const int bx = blockIdx.x;
  const int tid = threadIdx.x;

  if (bx >= NGEMM) {
    int j = bx - NGEMM;
    mlp_block(tid, j * 256, lds, T, W1b + (size_t)hop * NHID * NW,
              b1 + hop * NHID, W2 + hop * NHID, b2[hop], out, accumulate);
    return;
  }

  // ---- GEMM path ----
  const int m0 = (bx >> 3) * 256, n0 = (bx & 7) * 256;
  const int lane = tid & 63, wv = tid >> 6;
  const int wm = wv >> 2, wn = wv & 3;
  const int l31 = lane & 31, hi = lane >> 5;
  const int fsw32 = (l31 >> 1) & 3;

  // staging source: rows srow and srow+128 of the 256-row half, chunk
  // pre-swizzled with f(row)=(row>>1)&3 (same f for row+128).
  const int srow = tid >> 2;
  const int scsw = (tid & 3) ^ ((srow >> 1) & 3);
  const bf16_t* aS = A + (size_t)(m0 + srow) * lda + scsw * 8;
  const bf16_t* bS = Bt + (size_t)(n0 + srow) * ldb + scsw * 8;

  // fragment read bases (row part only; 32-row-group + chunk added per read)
  const bf16_t* pA = lds + (size_t)(wm * 128 + l31) * 32;
  const bf16_t* pB = lds + 16384 + (size_t)(wn * 64 + l31) * 32;

  floatx16 acc[4][2];
#pragma unroll
  for (int mf = 0; mf < 4; ++mf)
#pragma unroll
    for (int nf = 0; nf < 2; ++nf)
#pragma unroll
      for (int r = 0; r < 16; ++r) acc[mf][nf][r] = 0.f;

  // prologue: stage tile0 (buf0, both K-halves) + tile1 ks0 (buf1);
  // vmcnt(8) leaves {buf0-ks1 A,B; buf1-ks0 A,B} in flight -> buf0-ks0 landed.
  STAGE2(aS, lda, 0, 0, 0);
  STAGE2(bS, ldb, 0, 0, 16384);
  STAGE2(aS, lda, 0, 1, 0);
  STAGE2(bS, ldb, 0, 1, 16384);
  STAGE2(aS, lda, 1, 0, 32768);
  STAGE2(bS, ldb, 1, 0, 49152);
  asm volatile("s_waitcnt vmcnt(8)" ::: "memory");
  TOPB;

  bf16x8 af0[4], af1[4], bf0[4], bf1[4];
  RD_B4(bf0, 0, 0);
  RD_A4(af0, 0, 0, 0);

  const int nt = K >> 6;    // K-tiles
  const int nit = K >> 7;   // iterations (2 K-tiles each)
#pragma unroll 1
  for (int i = 0; i < nit; ++i) {
    const int t1 = 2 * i + 1;
    const int t2 = (t1 + 1 < nt) ? t1 + 1 : 0;  // clamp: keep vmcnt counts uniform
    const int t3 = (t1 + 2 < nt) ? t1 + 2 : 0;
    // p1: compute (buf0,ks0,mh0); prefetch A(buf0,ks0,mh1)
    RD_A4(af1, 0, 0, 1);
    MM(af0, bf0, 0);
    STAGE2(aS, lda, t1, 1, 32768);
    ENDB;
    // p2: compute (buf0,ks0,mh1); prefetch B+A(buf0,ks1)
    VM6; TOPB;
    RD_B4(bf1, 0, 1);
    RD_A4(af0, 0, 1, 0);
    MM(af1, bf0, 1);
    STAGE2(bS, ldb, t1, 1, 49152);
    ENDB;
    // p3: compute (buf0,ks1,mh0); prefetch A(buf0,ks1,mh1)
    RD_A4(af1, 0, 1, 1);
    MM(af0, bf1, 0);
    STAGE2(aS, lda, t2, 0, 0);
    ENDB;
    // p4: compute (buf0,ks1,mh1); prefetch B+A(buf1,ks0)
    VM6; TOPB;
    RD_B4(bf0, 32768, 0);
    RD_A4(af0, 32768, 0, 0);
    MM(af1, bf1, 1);
    STAGE2(bS, ldb, t2, 0, 16384);
    ENDB;
    // p5: compute (buf1,ks0,mh0); prefetch A(buf1,ks0,mh1)
    RD_A4(af1, 32768, 0, 1);
    MM(af0, bf0, 0);
    STAGE2(aS, lda, t2, 1, 0);
    ENDB;
    // p6: compute (buf1,ks0,mh1); prefetch B+A(buf1,ks1)
    VM6; TOPB;
    RD_B4(bf1, 32768, 1);
    RD_A4(af0, 32768, 1, 0);
    MM(af1, bf0, 1);
    STAGE2(bS, ldb, t2, 1, 16384);
    ENDB;
    // p7: compute (buf1,ks1,mh0); prefetch A(buf1,ks1,mh1)
    RD_A4(af1, 32768, 1, 1);
    MM(af0, bf1, 0);
    STAGE2(aS, lda, t3, 0, 32768);
    ENDB;
    // p8: compute (buf1,ks1,mh1); prefetch B+A(buf0,ks0) [next iter's tile]
    VM6; TOPB;
    RD_B4(bf0, 0, 0);
    RD_A4(af0, 0, 0, 0);
    MM(af1, bf1, 1);
    STAGE2(bS, ldb, t3, 0, 49152);
    ENDB;
  }
  asm volatile("s_waitcnt vmcnt(0)" ::: "memory");

  // epilogue (32x32x16 C/D map): col = n0+wn*64+nf*32+l31;
  // rows rowb..rowb+3 with rowb = m0+wm*128+mf*32+4*hi+8*g, regs g*4..g*4+3
#pragma unroll
  for (int mf = 0; mf < 4; ++mf) {
#pragma unroll
    for (int nf = 0; nf < 2; ++nf) {
      int col = n0 + wn * 64 + nf * 32 + l31;
#pragma unroll
      for (int g = 0; g < 4; ++g) {
        int rowb = m0 + wm * 128 + mf * 32 + 4 * hi + 8 * g;
        bf16x4 tv;
#pragma unroll
        for (int r = 0; r < 4; ++r) tv[r] = (bf16_t)acc[mf][nf][g * 4 + r];
        *(bf16x4*)(Ct + (size_t)col * ldct + rowb) = tv;
        if (write_c) {
#pragma unroll
          for (int r = 0; r < 4; ++r)
            C[(size_t)(rowb + r) * ldc + col] = tv[r];
        }
      }
    }
  }
}

// Standalone MLP (hop 6 tail): 512-thread, 256-row blocks.
__global__ __launch_bounds__(512) void mlp_score_kernel(
    const bf16_t* __restrict__ T, const bf16_t* __restrict__ W1b,
    const float* __restrict__ b1, const float* __restrict__ W2,
    const float* __restrict__ b2, float* __restrict__ out,
    int hop, int accumulate) {
  __shared__ bf16_t Bs[25600];  // 48KB W1 tile + 2KB sred
  mlp_block(threadIdx.x, blockIdx.x * 256, Bs, T,
            W1b + (size_t)hop * NHID * NW, b1 + hop * NHID, W2 + hop * NHID,
            b2[hop], out, accumulate);
}

extern "C" void kernel_launch(void* const* d_in, const int* in_sizes, int n_in,
                              void* d_out, int out_size, void* d_ws, size_t ws_size,
                              hipStream_t stream) {
  const float* x = (const float*)d_in[0];
  const float* L = (const float*)d_in[1];
  const float* W1 = (const float*)d_in[2];
  const float* b1 = (const float*)d_in[3];
  const float* W2 = (const float*)d_in[4];
  const float* b2 = (const float*)d_in[5];
  float* out = (float*)d_out;

  char* ws = (char*)d_ws;
  size_t off = 0;
  auto walloc = [&](size_t bytes) -> void* {
    off = (off + 255) & ~(size_t)255;
    void* p = ws + off;
    off += bytes;
    return p;
  };
  bf16_t* Xb = (bf16_t*)walloc((size_t)NBW * NM * 2);   // Tt_0 = x cast: [(b,w)][m]
  bf16_t* XT0 = (bf16_t*)walloc((size_t)NM * NBW * 2);  // [m][(b,w)] MLP input, buf 0
  bf16_t* XT1 = (bf16_t*)walloc((size_t)NM * NBW * 2);  // [m][(b,w)] MLP input, buf 1
  bf16_t* Lb = (bf16_t*)walloc((size_t)NM * NM * 2);    // L bf16 (NT B-operand)
  bf16_t* W1b = (bf16_t*)walloc((size_t)7 * NHID * NW * 2);
  bf16_t* Ta = (bf16_t*)walloc((size_t)NBW * NM * 2);   // ping-pong partner of Xb
  (void)ws_size; (void)in_sizes; (void)n_in; (void)out_size;

  // merged prep: prep_x (2688 blocks) + cast L (1024) + cast W1 (64)
  prep_all_kernel<<<dim3(3776), dim3(256), 0, stream>>>(x, Xb, XT0, L, Lb, W1, W1b);

  // Fused chain: launch i computes gemm hop i (Tt_i + XT_i) on blocks 0-167
  // and mlp hop i-1 (reading XT_{i-1}) on blocks 168-423.
  bf16_t* src = Xb;
  bf16_t* dst = Ta;
  bf16_t* xtprev = XT0;
  bf16_t* xtcur = XT1;
  for (int i = 1; i <= 6; ++i) {
    fused_gemm_mlp_kernel<<<dim3(NGEMM + NMLPB), dim3(512), 0, stream>>>(
        src, Lb, dst, xtcur, NM, NM, NM, NM, NBW, (i < 6) ? 1 : 0,
        xtprev, W1b, b1, W2, b2, out, i - 1, (i > 1) ? 1 : 0);
    bf16_t* t = src; src = dst; dst = t;
    t = xtprev; xtprev = xtcur; xtcur = t;
  }
  // tail: mlp hop 6 on the last XT
  mlp_score_kernel<<<dim3(NM * NB / 256), dim3(512), 0, stream>>>(
      xtprev, W1b, b1, W2, b2, out, 6, 1);
}

// Round 9
// 460.232 us; speedup vs baseline: 1.1814x; 1.0549x over previous
//
#include <hip/hip_runtime.h>
#include <cstdint>
#include <cstddef>

typedef __bf16 bf16_t;
typedef __attribute__((ext_vector_type(8))) __bf16 bf16x8;
typedef __attribute__((ext_vector_type(4))) __bf16 bf16x4;
typedef __attribute__((ext_vector_type(4))) float floatx4;

#define NB 32
#define NW 168
#define NM 2048
#define NHID 128
#define NBW (NB * NW)  // 5376
#define NGEMM 168      // 21 m-tiles x 8 n-tiles of 256^2
#define NMLPB 256      // 256-row mlp blocks

#define GLOAD_LDS16(g, l)                                          \
  __builtin_amdgcn_global_load_lds(                                \
      (const __attribute__((address_space(1))) void*)(g),          \
      (__attribute__((address_space(3))) void*)(l), 16, 0, 0)

// ---------------------------------------------------------------------------
// Merged prep (r8-verified): blocks [0,2688) = prep_x 64x64 tiles (cast +
// transpose); [2688,3712) = cast L; [3712,3776) = cast W1. Deterministic:
// disjoint writes, block-uniform branches, barrier only in the tile branch.
// ---------------------------------------------------------------------------
__global__ void prep_all_kernel(const float* __restrict__ x, bf16_t* __restrict__ Xb,
                                bf16_t* __restrict__ XT, const float* __restrict__ L,
                                bf16_t* __restrict__ Lb, const float* __restrict__ W1,
                                bf16_t* __restrict__ W1b) {
  __shared__ float tile[64][65];
  const int bx = blockIdx.x;
  const int t = threadIdx.x;
  if (bx < 2688) {
    const int R = NBW, C = NM;
    int r0 = (bx >> 5) * 64, c0 = (bx & 31) * 64;
    int tr = t >> 4, tc4 = (t & 15) * 4;
#pragma unroll
    for (int p = 0; p < 4; ++p) {
      int row = p * 16 + tr;
      float4 v = *(const float4*)(x + (size_t)(r0 + row) * C + c0 + tc4);
      tile[row][tc4 + 0] = v.x;
      tile[row][tc4 + 1] = v.y;
      tile[row][tc4 + 2] = v.z;
      tile[row][tc4 + 3] = v.w;
      bf16x4 o = {(bf16_t)v.x, (bf16_t)v.y, (bf16_t)v.z, (bf16_t)v.w};
      *(bf16x4*)(Xb + (size_t)(r0 + row) * C + c0 + tc4) = o;
    }
    __syncthreads();
#pragma unroll
    for (int p = 0; p < 4; ++p) {
      int c = p * 16 + tr;
      bf16x4 o = {(bf16_t)tile[tc4 + 0][c], (bf16_t)tile[tc4 + 1][c],
                  (bf16_t)tile[tc4 + 2][c], (bf16_t)tile[tc4 + 3][c]};
      *(bf16x4*)(XT + (size_t)(c0 + c) * R + r0 + tc4) = o;
    }
  } else if (bx < 3712) {
    const int n4 = NM * NM / 4;
    for (int i = (bx - 2688) * 256 + t; i < n4; i += 1024 * 256) {
      float4 v = ((const float4*)L)[i];
      bf16x4 o = {(bf16_t)v.x, (bf16_t)v.y, (bf16_t)v.z, (bf16_t)v.w};
      ((bf16x4*)Lb)[i] = o;
    }
  } else {
    const int n4 = 7 * NHID * NW / 4;
    for (int i = (bx - 3712) * 256 + t; i < n4; i += 64 * 256) {
      float4 v = ((const float4*)W1)[i];
      bf16x4 o = {(bf16_t)v.x, (bf16_t)v.y, (bf16_t)v.z, (bf16_t)v.w};
      ((bf16x4*)W1b)[i] = o;
    }
  }
}

// ---------------------------------------------------------------------------
// mlp body (r6/r8-verified): one 256-row MLP sub-block, 512 threads, ALL 8
// waves compute (4m x 2n; wave out 64 rows x 64 hid). All 512 threads stage
// W1 (3072 chunks = 6/thread; pads zeroed). K=168 padded to 192, W1 in
// [kc][h] chunk layout with XOR swizzle. Barriers unconditional.
// ---------------------------------------------------------------------------
__device__ __forceinline__ void mlp_block(
    int tid, int r0, bf16_t* __restrict__ Bs,
    const bf16_t* __restrict__ T, const bf16_t* __restrict__ Wh,
    const float* __restrict__ b1h, const float* __restrict__ w2h, float b2v,
    float* __restrict__ out, int accumulate) {
  float* sred = (float*)(Bs + 24576);  // 512 floats after the 48KB W1 tile
  int lane = tid & 63, wv2 = tid >> 6;

#pragma unroll
  for (int i = 0; i < 6; ++i) {
    int c = i * 512 + tid;
    if (c >= 2688) {
      int4 z = {0, 0, 0, 0};
      *(int4*)(Bs + (size_t)c * 8) = z;
    } else {
      int kc = c >> 7;
      int h = (c & 127) ^ ((kc & 3) << 2);
      GLOAD_LDS16(Wh + (size_t)h * NW + kc * 8, Bs + (size_t)(i * 512 + wv2 * 64) * 8);
    }
  }
  __syncthreads();  // staging (incl. async loads) complete

  {
    int wm = wv2 >> 1, wn = wv2 & 1;
    int quad = lane >> 4, l15 = lane & 15;
    const bf16_t* arow[4];
#pragma unroll
    for (int mi = 0; mi < 4; ++mi) {
      int R = r0 + wm * 64 + mi * 16 + l15;
      arow[mi] = T + (size_t)(R >> 5) * NBW + (size_t)(R & 31) * NW + quad * 8;
    }
    floatx4 zero4 = {0.f, 0.f, 0.f, 0.f};
    floatx4 acc[4][4];
#pragma unroll
    for (int mi = 0; mi < 4; ++mi)
#pragma unroll
      for (int ni = 0; ni < 4; ++ni) acc[mi][ni] = zero4;

#pragma unroll
    for (int kb = 0; kb < 192; kb += 32) {
      int kc = (kb >> 3) + quad;
      bf16x8 af[4], bf[4];
#pragma unroll
      for (int mi = 0; mi < 4; ++mi)
        af[mi] = *(const bf16x8*)(arow[mi] + kb);  // k>=168 reads garbage; B pad=0
#pragma unroll
      for (int ni = 0; ni < 4; ++ni) {
        int hpos = (wn * 64 + ni * 16 + l15) ^ ((kc & 3) << 2);
        bf[ni] = *(const bf16x8*)(Bs + (size_t)(kc * 128 + hpos) * 8);
      }
#pragma unroll
      for (int mi = 0; mi < 4; ++mi)
#pragma unroll
        for (int ni = 0; ni < 4; ++ni)
          acc[mi][ni] = __builtin_amdgcn_mfma_f32_16x16x32_bf16(af[mi], bf[ni], acc[mi][ni], 0, 0, 0);
    }

    float part[4][4];
#pragma unroll
    for (int mi = 0; mi < 4; ++mi)
#pragma unroll
      for (int r = 0; r < 4; ++r) part[mi][r] = 0.f;
#pragma unroll
    for (int ni = 0; ni < 4; ++ni) {
      int col = wn * 64 + ni * 16 + l15;
      float b1v = b1h[col];
      float w2v = w2h[col];
#pragma unroll
      for (int mi = 0; mi < 4; ++mi)
#pragma unroll
        for (int r = 0; r < 4; ++r) {
          float h = acc[mi][ni][r] + b1v;
          h = h > 0.f ? h : 0.f;
          part[mi][r] += h * w2v;
        }
    }
#pragma unroll
    for (int off = 1; off < 16; off <<= 1)
#pragma unroll
      for (int mi = 0; mi < 4; ++mi)
#pragma unroll
        for (int r = 0; r < 4; ++r) part[mi][r] += __shfl_xor(part[mi][r], off);
    if (l15 == 0) {
#pragma unroll
      for (int mi = 0; mi < 4; ++mi)
#pragma unroll
        for (int r = 0; r < 4; ++r) sred[wv2 * 64 + mi * 16 + quad * 4 + r] = part[mi][r];
    }
  }
  __syncthreads();
  if (tid < 256) {
    int wm = tid >> 6;
    int lr = tid & 63;
    float v = sred[(wm * 2) * 64 + lr] + sred[(wm * 2 + 1) * 64 + lr] + b2v;
    int R = r0 + wm * 64 + lr;
    int idx = (R & 31) * NM + (R >> 5);  // out[b*M + m]
    if (accumulate)
      out[idx] += v;
    else
      out[idx] = v;
  }
}

// ---------------------------------------------------------------------------
// Fused launch: blocks [0,NGEMM) run a 256x256 8-phase NT GEMM tile; blocks
// [NGEMM,+NMLPB) run one 256-row MLP sub-block of the PREVIOUS hop.
//
// Round-9 GEMM: round-4 VERBATIM (best measured 64.4us, tripwire-passed).
// Register fragment double-buffer: phase p issues ds_reads for phase p+1's
// fragments before phase p's MFMA cluster; counted vmcnt(6) + s_barrier at
// the top of even phases; 16x16x32 MFMA (the r8 32x32x16 swap produced
// unexplained ~2-way ds_read conflicts, +4.2M cycles -> reverted).
// ---------------------------------------------------------------------------
#define STAGE2(gbase, ld, t, ks, ldsbase)                                        \
  do {                                                                           \
    const bf16_t* _g = (gbase) + (size_t)(t) * 64 + (ks) * 32;                   \
    GLOAD_LDS16(_g, lds + (ldsbase) + (ks) * 8192 + wv * 512);                   \
    GLOAD_LDS16(_g + (size_t)128 * (ld),                                         \
                lds + (ldsbase) + (ks) * 8192 + 4096 + wv * 512);                \
  } while (0)

#define VM6 asm volatile("s_waitcnt vmcnt(6)" ::: "memory")
#define TOPB asm volatile("s_barrier" ::: "memory")
#define ENDB __builtin_amdgcn_s_barrier()

#define RD_A(dst, bufoff, ks, mh)                                                \
  _Pragma("unroll") for (int mi = 0; mi < 4; ++mi)                               \
      dst[mi] = *(const bf16x8*)(pA + (bufoff) + (ks) * 8192 + ((mh) * 4 + mi) * 512)

#define RD_B(dst, bufoff, ks)                                                    \
  _Pragma("unroll") for (int ni = 0; ni < 4; ++ni)                               \
      dst[ni] = *(const bf16x8*)(pB + (bufoff) + (ks) * 8192 + ni * 512)

#define MM16(af_, bf_, mh)                                                       \
  do {                                                                           \
    __builtin_amdgcn_s_setprio(1);                                               \
    _Pragma("unroll") for (int mi = 0; mi < 4; ++mi)                             \
        _Pragma("unroll") for (int ni = 0; ni < 4; ++ni)                         \
            acc[(mh) * 4 + mi][ni] = __builtin_amdgcn_mfma_f32_16x16x32_bf16(    \
                af_[mi], bf_[ni], acc[(mh) * 4 + mi][ni], 0, 0, 0);              \
    __builtin_amdgcn_s_setprio(0);                                               \
  } while (0)

__global__ __launch_bounds__(512, 2) void fused_gemm_mlp_kernel(
    const bf16_t* __restrict__ A, const bf16_t* __restrict__ Bt,
    bf16_t* __restrict__ C, bf16_t* __restrict__ Ct,
    int K, int lda, int ldb, int ldc, int ldct, int write_c,
    const bf16_t* __restrict__ T, const bf16_t* __restrict__ W1b,
    const float* __restrict__ b1, const float* __restrict__ W2,
    const float* __restrict__ b2, float* __restrict__ out,
    int hop, int accumulate) {
  __shared__ bf16_t lds[65536];  // 128 KiB union
  const int bx = blockIdx.x;
  const int tid = threadIdx.x;

  if (bx >= NGEMM) {
    int j = bx - NGEMM;
    mlp_block(tid, j * 256, lds, T, W1b + (size_t)hop * NHID * NW,
              b1 + hop * NHID, W2 + hop * NHID, b2[hop], out, accumulate);
    return;
  }

  // ---- GEMM path ----
  const int m0 = (bx >> 3) * 256, n0 = (bx & 7) * 256;
  const int lane = tid & 63, wv = tid >> 6;
  const int wm = wv >> 2, wn = wv & 3;
  const int quad = lane >> 4, l15 = lane & 15;

  // staging source: rows srow and srow+128 of the 256-row half, chunk
  // pre-swizzled with f(row)=(row>>1)&3 (same f for row+128).
  const int srow = tid >> 2;
  const int scsw = (tid & 3) ^ ((srow >> 1) & 3);
  const bf16_t* aS = A + (size_t)(m0 + srow) * lda + scsw * 8;
  const bf16_t* bS = Bt + (size_t)(n0 + srow) * ldb + scsw * 8;

  // fragment read base: row*32 + swizzled chunk, f(row)=(l15>>1)&3
  const int fsw = (quad ^ ((l15 >> 1) & 3)) * 8;
  const bf16_t* pA = lds + (size_t)(wm * 128 + l15) * 32 + fsw;
  const bf16_t* pB = lds + 16384 + (size_t)(wn * 64 + l15) * 32 + fsw;

  floatx4 zero4 = {0.f, 0.f, 0.f, 0.f};
  floatx4 acc[8][4];
#pragma unroll
  for (int mi = 0; mi < 8; ++mi)
#pragma unroll
    for (int ni = 0; ni < 4; ++ni) acc[mi][ni] = zero4;

  // prologue: stage tile0 (buf0, both halves) + tile1 ks0 (buf1); wait for
  // tile0-ks0 (8 newer loads in flight), then pre-read phase-1's fragments.
  STAGE2(aS, lda, 0, 0, 0);
  STAGE2(bS, ldb, 0, 0, 16384);
  STAGE2(aS, lda, 0, 1, 0);
  STAGE2(bS, ldb, 0, 1, 16384);
  STAGE2(aS, lda, 1, 0, 32768);
  STAGE2(bS, ldb, 1, 0, 49152);
  asm volatile("s_waitcnt vmcnt(8)" ::: "memory");
  TOPB;

  bf16x8 af0[4], af1[4], bf0[4], bf1[4];
  RD_B(bf0, 0, 0);
  RD_A(af0, 0, 0, 0);

  const int nt = K >> 6;    // K-tiles
  const int nit = K >> 7;   // iterations (2 K-tiles each)
#pragma unroll 1
  for (int i = 0; i < nit; ++i) {
    const int t1 = 2 * i + 1;
    const int t2 = (t1 + 1 < nt) ? t1 + 1 : 0;  // clamp: keep vmcnt counts uniform
    const int t3 = (t1 + 2 < nt) ? t1 + 2 : 0;
    // p1: compute (buf0,ks0,mh0); prefetch A(buf0,ks0,mh1)
    RD_A(af1, 0, 0, 1);
    MM16(af0, bf0, 0);
    STAGE2(aS, lda, t1, 1, 32768);
    ENDB;
    // p2: compute (buf0,ks0,mh1); prefetch B+A(buf0,ks1)
    VM6; TOPB;
    RD_B(bf1, 0, 1);
    RD_A(af0, 0, 1, 0);
    MM16(af1, bf0, 1);
    STAGE2(bS, ldb, t1, 1, 49152);
    ENDB;
    // p3: compute (buf0,ks1,mh0); prefetch A(buf0,ks1,mh1)
    RD_A(af1, 0, 1, 1);
    MM16(af0, bf1, 0);
    STAGE2(aS, lda, t2, 0, 0);
    ENDB;
    // p4: compute (buf0,ks1,mh1); prefetch B+A(buf1,ks0)
    VM6; TOPB;
    RD_B(bf0, 32768, 0);
    RD_A(af0, 32768, 0, 0);
    MM16(af1, bf1, 1);
    STAGE2(bS, ldb, t2, 0, 16384);
    ENDB;
    // p5: compute (buf1,ks0,mh0); prefetch A(buf1,ks0,mh1)
    RD_A(af1, 32768, 0, 1);
    MM16(af0, bf0, 0);
    STAGE2(aS, lda, t2, 1, 0);
    ENDB;
    // p6: compute (buf1,ks0,mh1); prefetch B+A(buf1,ks1)
    VM6; TOPB;
    RD_B(bf1, 32768, 1);
    RD_A(af0, 32768, 1, 0);
    MM16(af1, bf0, 1);
    STAGE2(bS, ldb, t2, 1, 16384);
    ENDB;
    // p7: compute (buf1,ks1,mh0); prefetch A(buf1,ks1,mh1)
    RD_A(af1, 32768, 1, 1);
    MM16(af0, bf1, 0);
    STAGE2(aS, lda, t3, 0, 32768);
    ENDB;
    // p8: compute (buf1,ks1,mh1); prefetch B+A(buf0,ks0) [next iter's tile]
    VM6; TOPB;
    RD_B(bf0, 0, 0);
    RD_A(af0, 0, 0, 0);
    MM16(af1, bf1, 1);
    STAGE2(bS, ldb, t3, 0, 49152);
    ENDB;
  }
  asm volatile("s_waitcnt vmcnt(0)" ::: "memory");

  // epilogue: C rows m0+wm*128+mi*16+quad*4+r, cols n0+wn*64+ni*16+l15
#pragma unroll
  for (int mi = 0; mi < 8; ++mi) {
#pragma unroll
    for (int ni = 0; ni < 4; ++ni) {
      int col = n0 + wn * 64 + ni * 16 + l15;
      int rowb = m0 + wm * 128 + mi * 16 + quad * 4;
      bf16x4 tv;
#pragma unroll
      for (int r = 0; r < 4; ++r) tv[r] = (bf16_t)acc[mi][ni][r];
      *(bf16x4*)(Ct + (size_t)col * ldct + rowb) = tv;
      if (write_c) {
#pragma unroll
        for (int r = 0; r < 4; ++r)
          C[(size_t)(rowb + r) * ldc + col] = tv[r];
      }
    }
  }
}

// Standalone MLP (hop 6 tail): 512-thread, 256-row blocks.
__global__ __launch_bounds__(512) void mlp_score_kernel(
    const bf16_t* __restrict__ T, const bf16_t* __restrict__ W1b,
    const float* __restrict__ b1, const float* __restrict__ W2,
    const float* __restrict__ b2, float* __restrict__ out,
    int hop, int accumulate) {
  __shared__ bf16_t Bs[25600];  // 48KB W1 tile + 2KB sred
  mlp_block(threadIdx.x, blockIdx.x * 256, Bs, T,
            W1b + (size_t)hop * NHID * NW, b1 + hop * NHID, W2 + hop * NHID,
            b2[hop], out, accumulate);
}

extern "C" void kernel_launch(void* const* d_in, const int* in_sizes, int n_in,
                              void* d_out, int out_size, void* d_ws, size_t ws_size,
                              hipStream_t stream) {
  const float* x = (const float*)d_in[0];
  const float* L = (const float*)d_in[1];
  const float* W1 = (const float*)d_in[2];
  const float* b1 = (const float*)d_in[3];
  const float* W2 = (const float*)d_in[4];
  const float* b2 = (const float*)d_in[5];
  float* out = (float*)d_out;

  char* ws = (char*)d_ws;
  size_t off = 0;
  auto walloc = [&](size_t bytes) -> void* {
    off = (off + 255) & ~(size_t)255;
    void* p = ws + off;
    off += bytes;
    return p;
  };
  bf16_t* Xb = (bf16_t*)walloc((size_t)NBW * NM * 2);   // Tt_0 = x cast: [(b,w)][m]
  bf16_t* XT0 = (bf16_t*)walloc((size_t)NM * NBW * 2);  // [m][(b,w)] MLP input, buf 0
  bf16_t* XT1 = (bf16_t*)walloc((size_t)NM * NBW * 2);  // [m][(b,w)] MLP input, buf 1
  bf16_t* Lb = (bf16_t*)walloc((size_t)NM * NM * 2);    // L bf16 (NT B-operand)
  bf16_t* W1b = (bf16_t*)walloc((size_t)7 * NHID * NW * 2);
  bf16_t* Ta = (bf16_t*)walloc((size_t)NBW * NM * 2);   // ping-pong partner of Xb
  (void)ws_size; (void)in_sizes; (void)n_in; (void)out_size;

  // merged prep: prep_x (2688 blocks) + cast L (1024) + cast W1 (64)
  prep_all_kernel<<<dim3(3776), dim3(256), 0, stream>>>(x, Xb, XT0, L, Lb, W1, W1b);

  // Fused chain: launch i computes gemm hop i (Tt_i + XT_i) on blocks 0-167
  // and mlp hop i-1 (reading XT_{i-1}) on blocks 168-423.
  bf16_t* src = Xb;
  bf16_t* dst = Ta;
  bf16_t* xtprev = XT0;
  bf16_t* xtcur = XT1;
  for (int i = 1; i <= 6; ++i) {
    fused_gemm_mlp_kernel<<<dim3(NGEMM + NMLPB), dim3(512), 0, stream>>>(
        src, Lb, dst, xtcur, NM, NM, NM, NM, NBW, (i < 6) ? 1 : 0,
        xtprev, W1b, b1, W2, b2, out, i - 1, (i > 1) ? 1 : 0);
    bf16_t* t = src; src = dst; dst = t;
    t = xtprev; xtprev = xtcur; xtcur = t;
  }
  // tail: mlp hop 6 on the last XT
  mlp_score_kernel<<<dim3(NM * NB / 256), dim3(512), 0, stream>>>(
      xtprev, W1b, b1, W2, b2, out, 6, 1);
}